// Round 3
// baseline (737.434 us; speedup 1.0000x reference)
//
#include <hip/hip_runtime.h>
#include <hip/hip_bf16.h>

#define E_ 16
#define D_ 4096
#define F_ 688
#define HS_ 704      // padded H row stride (bf16 elems)
#define N_ 8192
#define CAP_ 640     // int(1.25 * 8192 / 16)

typedef __attribute__((ext_vector_type(8))) short bf16x8;
typedef __attribute__((ext_vector_type(4))) float f32x4;
typedef __attribute__((ext_vector_type(4))) float fvec4;
typedef __attribute__((ext_vector_type(8))) unsigned short usvec8;

__device__ __forceinline__ unsigned short f2bf(float f) {
    __hip_bfloat16 h = __float2bfloat16(f);
    return __builtin_bit_cast(unsigned short, h);
}
// XOR-swizzled LDS index: tiles are [rows][64] bf16; 16B unit index XORed with row&7.
__device__ __forceinline__ int lidx(int row, int k) {
    return row * 64 + (((k >> 3) ^ (row & 7)) << 3) + (k & 7);
}

// ---------------- dispatch: stable per-expert positions ----------------
__global__ void k_dispatch(const int* __restrict__ idx,
                           int* __restrict__ slot_token,
                           int* __restrict__ row_of,
                           int* __restrict__ cnt) {
    __shared__ int hist[256][E_];
    const int t = threadIdx.x;
#pragma unroll
    for (int e = 0; e < E_; e++) hist[t][e] = 0;
    __syncthreads();
    const int base = t * (N_ / 256);
    for (int j = 0; j < N_ / 256; j++) {
        int e = idx[base + j];
        hist[t][e]++;
    }
    __syncthreads();
    if (t < E_) {
        int run = 0;
        for (int i = 0; i < 256; i++) { int v = hist[i][t]; hist[i][t] = run; run += v; }
        cnt[t] = run < CAP_ ? run : CAP_;
    }
    for (int s = t; s < E_ * CAP_; s += 256) slot_token[s] = -1;
    __syncthreads();
    for (int j = 0; j < N_ / 256; j++) {
        int i = base + j;
        int e = idx[i];
        int p = hist[t][e]++;
        if (p < CAP_) { slot_token[e * CAP_ + p] = i; row_of[i] = e * CAP_ + p; }
        else          { row_of[i] = -1; }
    }
}

// ---------------- zero the (rare) dropped-token rows ----------------
__global__ void k_zero_dropped(const int* __restrict__ row_of, float* __restrict__ y) {
    const int i = blockIdx.x;
    if (row_of[i] >= 0) return;
    fvec4* yp = (fvec4*)(y + (size_t)i * D_);
    fvec4 z = {0.f, 0.f, 0.f, 0.f};
    for (int c = threadIdx.x; c < D_ / 4; c += 256) yp[c] = z;
}

// ---------------- gather x -> bf16 Abuf[E*CAP][D] ----------------
__global__ void k_gather(const float* __restrict__ x, const int* __restrict__ slot_token,
                         unsigned short* __restrict__ Abuf) {
    const int slot = blockIdx.x;
    const int t = slot_token[slot];
    usvec8* dst = (usvec8*)(Abuf + (size_t)slot * D_);
    if (t < 0) {
        usvec8 z = {0, 0, 0, 0, 0, 0, 0, 0};
        for (int c = threadIdx.x; c < D_ / 8; c += 256) dst[c] = z;
    } else {
        const fvec4* src = (const fvec4*)(x + (size_t)t * D_);
        for (int c = threadIdx.x; c < D_ / 8; c += 256) {
            fvec4 a = src[2 * c], b = src[2 * c + 1];
            usvec8 p = {f2bf(a[0]), f2bf(a[1]), f2bf(a[2]), f2bf(a[3]),
                        f2bf(b[0]), f2bf(b[1]), f2bf(b[2]), f2bf(b[3])};
            dst[c] = p;
        }
    }
}

// ================= GEMM1: H = silu(X*Wg) * (X*Wu) =================
#define G1_LOAD(rA, rG, rU, KC)                                               \
  {                                                                           \
    if (PRE) {                                                                \
      _Pragma("unroll") for (int rep = 0; rep < 2; rep++)                     \
      _Pragma("unroll") for (int s = 0; s < 2; s++)                           \
        rA[rep * 2 + s] = *(const usvec8*)&Ae[(size_t)(ar + rep * 64) * D_ + (KC) + ak + s * 8]; \
    }                                                                         \
    _Pragma("unroll") for (int r = 0; r < 8; r++) {                           \
      size_t off = (size_t)((KC) + kq8 + r) * F_ + gf;                        \
      rG[r] = bvalid ? *(const float2*)(WgE + off) : fz2;                     \
      rU[r] = bvalid ? *(const float2*)(WuE + off) : fz2;                     \
    }                                                                         \
  }

#define G1_STORE(rA, rG, rU, KC)                                              \
  {                                                                           \
    if (PRE) {                                                                \
      _Pragma("unroll") for (int rep = 0; rep < 2; rep++)                     \
      _Pragma("unroll") for (int s = 0; s < 2; s++)                           \
        *(usvec8*)&As[lidx(ar + rep * 64, ak + s * 8)] = rA[rep * 2 + s];     \
    } else {                                                                  \
      _Pragma("unroll") for (int rep = 0; rep < 2; rep++) {                   \
        int row = ar + rep * 64;                                              \
        int t = tokS[row];                                                    \
        const float* src = x + (size_t)(t < 0 ? 0 : t) * D_ + (KC) + ak;      \
        fvec4 v0 = {0.f,0.f,0.f,0.f}, v1 = v0, v2 = v0, v3 = v0;              \
        if (t >= 0) { v0 = *(const fvec4*)src; v1 = *(const fvec4*)(src + 4); \
                      v2 = *(const fvec4*)(src + 8); v3 = *(const fvec4*)(src + 12); } \
        usvec8 p0 = {f2bf(v0[0]), f2bf(v0[1]), f2bf(v0[2]), f2bf(v0[3]),      \
                     f2bf(v1[0]), f2bf(v1[1]), f2bf(v1[2]), f2bf(v1[3])};     \
        usvec8 p1 = {f2bf(v2[0]), f2bf(v2[1]), f2bf(v2[2]), f2bf(v2[3]),      \
                     f2bf(v3[0]), f2bf(v3[1]), f2bf(v3[2]), f2bf(v3[3])};     \
        *(usvec8*)&As[lidx(row, ak)] = p0;                                    \
        *(usvec8*)&As[lidx(row, ak + 8)] = p1;                                \
      }                                                                       \
    }                                                                         \
    usvec8 pg0, pg1, pu0, pu1;                                                \
    _Pragma("unroll") for (int r = 0; r < 8; r++) {                           \
      pg0[r] = (short)f2bf(rG[r].x); pg1[r] = (short)f2bf(rG[r].y);           \
      pu0[r] = (short)f2bf(rU[r].x); pu1[r] = (short)f2bf(rU[r].y);           \
    }                                                                         \
    *(usvec8*)&Bgs[lidx(fpos, kq8)]     = pg0;                                \
    *(usvec8*)&Bgs[lidx(fpos + 1, kq8)] = pg1;                                \
    *(usvec8*)&Bus[lidx(fpos, kq8)]     = pu0;                                \
    *(usvec8*)&Bus[lidx(fpos + 1, kq8)] = pu1;                                \
  }

#define G1_COMPUTE                                                            \
  {                                                                           \
    __builtin_amdgcn_s_setprio(1);                                            \
    _Pragma("unroll") for (int kk = 0; kk < 64; kk += 32) {                   \
      const int ko = kk + ((lane >> 4) << 3);                                 \
      bf16x8 av[4], bgv[2], buv[2];                                           \
      _Pragma("unroll") for (int mi = 0; mi < 4; mi++)                        \
        av[mi] = *(const bf16x8*)&As[lidx(wm * 64 + mi * 16 + (lane & 15), ko)]; \
      _Pragma("unroll") for (int ni = 0; ni < 2; ni++) {                      \
        int rr = wn * 32 + ni * 16 + (lane & 15);                             \
        bgv[ni] = *(const bf16x8*)&Bgs[lidx(rr, ko)];                         \
        buv[ni] = *(const bf16x8*)&Bus[lidx(rr, ko)];                         \
      }                                                                       \
      _Pragma("unroll") for (int mi = 0; mi < 4; mi++)                        \
      _Pragma("unroll") for (int ni = 0; ni < 2; ni++) {                      \
        accG[mi][ni] = __builtin_amdgcn_mfma_f32_16x16x32_bf16(av[mi], bgv[ni], accG[mi][ni], 0, 0, 0); \
        accU[mi][ni] = __builtin_amdgcn_mfma_f32_16x16x32_bf16(av[mi], buv[ni], accU[mi][ni], 0, 0, 0); \
      }                                                                       \
    }                                                                         \
    __builtin_amdgcn_s_setprio(0);                                            \
  }

template <bool PRE>
__global__ __launch_bounds__(256, 3) void k_gemm1(
    const float* __restrict__ x, const unsigned short* __restrict__ Abuf,
    const float* __restrict__ Wg, const float* __restrict__ Wu,
    const int* __restrict__ slot_token, const int* __restrict__ cnt,
    unsigned short* __restrict__ H) {
    const int bid = blockIdx.x;           // 880 = 8 xcd * 22 groups * 5 m
    const int xcd = bid & 7;
    const int j = bid >> 3;
    const int mb = j % 5;
    const int gl = j / 5;
    const int group = xcd * 22 + gl;
    const int e = group / 11, fidx = group % 11;
    const int m0 = mb * 128, f0 = fidx * 64;
    if (m0 >= cnt[e]) return;

    __shared__ __align__(16) unsigned short As[128 * 64];
    __shared__ __align__(16) unsigned short Bgs[64 * 64];
    __shared__ __align__(16) unsigned short Bus[64 * 64];
    __shared__ int tokS[128];

    const int tid = threadIdx.x;
    const int lane = tid & 63, wave = tid >> 6;
    const int wm = wave >> 1, wn = wave & 1;

    if (!PRE) {
        if (tid < 128) tokS[tid] = slot_token[e * CAP_ + m0 + tid];
        __syncthreads();
    }

    f32x4 accG[4][2], accU[4][2];
#pragma unroll
    for (int a = 0; a < 4; a++)
#pragma unroll
        for (int b = 0; b < 2; b++) {
            f32x4 z = {0.f, 0.f, 0.f, 0.f};
            accG[a][b] = z; accU[a][b] = z;
        }

    const int ar = tid >> 2, ak = (tid & 3) * 16;        // A staging: 4 lanes/row, 16B chunks
    const int fpos = (tid & 31) * 2, kq8 = (tid >> 5) * 8; // B staging: float2 per f-pair
    const int gf = f0 + fpos;
    const bool bvalid = gf < F_;                          // gf even, F even -> pair-valid
    const float2 fz2 = {0.f, 0.f};
    const float* WgE = Wg + (size_t)e * D_ * F_;
    const float* WuE = Wu + (size_t)e * D_ * F_;
    const unsigned short* Ae = Abuf + (size_t)(e * CAP_ + m0) * D_;

    usvec8 rA0[4], rA1[4];
    float2 rG0[8], rG1[8], rU0[8], rU1[8];

    G1_LOAD(rA0, rG0, rU0, 0)
    for (int t = 0; t < 62; t += 2) {
        G1_STORE(rA0, rG0, rU0, t * 64)
        __syncthreads();
        G1_LOAD(rA1, rG1, rU1, (t + 1) * 64)
        G1_COMPUTE
        __syncthreads();
        G1_STORE(rA1, rG1, rU1, (t + 1) * 64)
        __syncthreads();
        G1_LOAD(rA0, rG0, rU0, (t + 2) * 64)
        G1_COMPUTE
        __syncthreads();
    }
    G1_STORE(rA0, rG0, rU0, 62 * 64)
    __syncthreads();
    G1_LOAD(rA1, rG1, rU1, 63 * 64)
    G1_COMPUTE
    __syncthreads();
    G1_STORE(rA1, rG1, rU1, 63 * 64)
    __syncthreads();
    G1_COMPUTE

    // ---- epilogue: fused SwiGLU, write bf16 H ----
#pragma unroll
    for (int mi = 0; mi < 4; mi++)
#pragma unroll
        for (int ni = 0; ni < 2; ni++) {
            int f = f0 + wn * 32 + ni * 16 + (lane & 15);
            if (f >= F_) continue;
            int rowb = m0 + wm * 64 + mi * 16 + ((lane >> 4) << 2);
#pragma unroll
            for (int q = 0; q < 4; q++) {
                float g = accG[mi][ni][q], u = accU[mi][ni][q];
                float h = g * u / (1.f + __expf(-g));
                H[(size_t)(e * CAP_ + rowb + q) * HS_ + f] = f2bf(h);
            }
        }
}

// ================= GEMM2: Y = H * Wd, scatter * score =================
#define G2_LOAD(rA, rB, KC)                                                   \
  {                                                                           \
    _Pragma("unroll") for (int rep = 0; rep < 2; rep++)                       \
    _Pragma("unroll") for (int s = 0; s < 2; s++)                             \
      rA[rep * 2 + s] = *(const usvec8*)&He[(size_t)(ar + rep * 64) * HS_ + (KC) + ak + s * 8]; \
    _Pragma("unroll") for (int r = 0; r < 8; r++) {                           \
      int kr = (KC) + kq8 + r;                                                \
      rB[r] = (kr < F_) ? *(const float2*)(WdE + (size_t)kr * D_ + gd) : fz2; \
    }                                                                         \
  }

#define G2_STORE(rA, rB)                                                      \
  {                                                                           \
    _Pragma("unroll") for (int rep = 0; rep < 2; rep++)                       \
    _Pragma("unroll") for (int s = 0; s < 2; s++)                             \
      *(usvec8*)&As[lidx(ar + rep * 64, ak + s * 8)] = rA[rep * 2 + s];       \
    usvec8 p0, p1;                                                            \
    _Pragma("unroll") for (int r = 0; r < 8; r++) {                           \
      p0[r] = (short)f2bf(rB[r].x); p1[r] = (short)f2bf(rB[r].y);             \
    }                                                                         \
    *(usvec8*)&Bts[lidx(dpos, kq8)]     = p0;                                 \
    *(usvec8*)&Bts[lidx(dpos + 1, kq8)] = p1;                                 \
  }

#define G2_COMPUTE                                                            \
  {                                                                           \
    __builtin_amdgcn_s_setprio(1);                                            \
    _Pragma("unroll") for (int kk = 0; kk < 64; kk += 32) {                   \
      const int ko = kk + ((lane >> 4) << 3);                                 \
      bf16x8 av[4], bv[2];                                                    \
      _Pragma("unroll") for (int mi = 0; mi < 4; mi++)                        \
        av[mi] = *(const bf16x8*)&As[lidx(wm * 64 + mi * 16 + (lane & 15), ko)]; \
      _Pragma("unroll") for (int ni = 0; ni < 2; ni++)                        \
        bv[ni] = *(const bf16x8*)&Bts[lidx(wn * 32 + ni * 16 + (lane & 15), ko)]; \
      _Pragma("unroll") for (int mi = 0; mi < 4; mi++)                        \
      _Pragma("unroll") for (int ni = 0; ni < 2; ni++)                        \
        acc[mi][ni] = __builtin_amdgcn_mfma_f32_16x16x32_bf16(av[mi], bv[ni], acc[mi][ni], 0, 0, 0); \
    }                                                                         \
    __builtin_amdgcn_s_setprio(0);                                            \
  }

__global__ __launch_bounds__(256, 3) void k_gemm2(
    const unsigned short* __restrict__ H, const float* __restrict__ Wd,
    const int* __restrict__ slot_token, const int* __restrict__ cnt,
    const float* __restrict__ scores, float* __restrict__ y) {
    const int bid = blockIdx.x;           // 5120 = 8 xcd * 128 groups * 5 m
    const int xcd = bid & 7;
    const int j = bid >> 3;
    const int mb = j % 5;
    const int gl = j / 5;
    const int group = xcd * 128 + gl;
    const int e = group >> 6, didx = group & 63;
    const int m0 = mb * 128, d0 = didx * 64;
    if (m0 >= cnt[e]) return;

    __shared__ __align__(16) unsigned short As[128 * 64];
    __shared__ __align__(16) unsigned short Bts[64 * 64];
    __shared__ int tokS[128];
    __shared__ float scS[128];

    const int tid = threadIdx.x;
    const int lane = tid & 63, wave = tid >> 6;
    const int wm = wave >> 1, wn = wave & 1;

    if (tid < 128) {
        int t = slot_token[e * CAP_ + m0 + tid];
        tokS[tid] = t;
        scS[tid] = (t >= 0) ? scores[t] : 0.f;
    }
    __syncthreads();

    f32x4 acc[4][2];
#pragma unroll
    for (int a = 0; a < 4; a++)
#pragma unroll
        for (int b = 0; b < 2; b++) {
            f32x4 z = {0.f, 0.f, 0.f, 0.f};
            acc[a][b] = z;
        }

    const int ar = tid >> 2, ak = (tid & 3) * 16;
    const int dpos = (tid & 31) * 2, kq8 = (tid >> 5) * 8;
    const int gd = d0 + dpos;
    const float2 fz2 = {0.f, 0.f};
    const float* WdE = Wd + (size_t)e * F_ * D_;
    const unsigned short* He = H + (size_t)(e * CAP_ + m0) * HS_;

    usvec8 rA0[4], rA1[4];
    float2 rB0[8], rB1[8];

    G2_LOAD(rA0, rB0, 0)
    for (int t = 0; t < 10; t += 2) {     // tiles 0..9
        G2_STORE(rA0, rB0)
        __syncthreads();
        G2_LOAD(rA1, rB1, (t + 1) * 64)
        G2_COMPUTE
        __syncthreads();
        G2_STORE(rA1, rB1)
        __syncthreads();
        G2_LOAD(rA0, rB0, (t + 2) * 64)
        G2_COMPUTE
        __syncthreads();
    }
    G2_STORE(rA0, rB0)                    // tile 10
    __syncthreads();
    G2_COMPUTE

    // ---- epilogue: scale by score, scatter to token rows ----
#pragma unroll
    for (int mi = 0; mi < 4; mi++)
#pragma unroll
        for (int ni = 0; ni < 2; ni++) {
            int d = d0 + wn * 32 + ni * 16 + (lane & 15);
            int rowb = wm * 64 + mi * 16 + ((lane >> 4) << 2);
#pragma unroll
            for (int q = 0; q < 4; q++) {
                int row = rowb + q;
                int t = tokS[row];
                if (t >= 0) y[(size_t)t * D_ + d] = acc[mi][ni][q] * scS[row];
            }
        }
}

extern "C" void kernel_launch(void* const* d_in, const int* in_sizes, int n_in,
                              void* d_out, int out_size, void* d_ws, size_t ws_size,
                              hipStream_t stream) {
    const float* x   = (const float*)d_in[0];
    const int*   idx = (const int*)d_in[1];
    const float* sc  = (const float*)d_in[2];
    const float* Wg  = (const float*)d_in[3];
    const float* Wu  = (const float*)d_in[4];
    const float* Wd  = (const float*)d_in[5];
    float* y = (float*)d_out;

    char* ws = (char*)d_ws;
    int* slot_token = (int*)ws;                              // E*CAP ints   = 40960 B
    int* row_of     = (int*)(ws + 40960);                    // N ints       = 32768 B
    int* cnt        = (int*)(ws + 40960 + 32768);            // E ints
    const size_t hoff = 131072;
    const size_t hbytes = (size_t)E_ * CAP_ * HS_ * 2;       // 14,417,920 B
    unsigned short* H = (unsigned short*)(ws + hoff);
    const size_t aoff = hoff + hbytes;
    const size_t abytes = (size_t)E_ * CAP_ * D_ * 2;        // 83,886,080 B
    unsigned short* Abuf = (unsigned short*)(ws + aoff);
    const bool pre = ws_size >= aoff + abytes;

    k_dispatch<<<1, 256, 0, stream>>>(idx, slot_token, row_of, cnt);
    k_zero_dropped<<<N_, 256, 0, stream>>>(row_of, y);
    if (pre) {
        k_gather<<<E_ * CAP_, 256, 0, stream>>>(x, slot_token, Abuf);
        k_gemm1<true><<<880, 256, 0, stream>>>(x, Abuf, Wg, Wu, slot_token, cnt, H);
    } else {
        k_gemm1<false><<<880, 256, 0, stream>>>(x, Abuf, Wg, Wu, slot_token, cnt, H);
    }
    k_gemm2<<<5120, 256, 0, stream>>>(H, Wd, slot_token, cnt, sc, y);
}

// Round 4
// 548.912 us; speedup vs baseline: 1.3434x; 1.3434x over previous
//
#include <hip/hip_runtime.h>
#include <hip/hip_bf16.h>

#define E_ 16
#define D_ 4096
#define F_ 688
#define HS_ 704      // padded H row stride (bf16 elems)
#define N_ 8192
#define CAP_ 640     // int(1.25 * 8192 / 16)

typedef __attribute__((ext_vector_type(8))) short bf16x8;
typedef __attribute__((ext_vector_type(4))) float f32x4;
typedef __attribute__((ext_vector_type(4))) float fvec4;
typedef __attribute__((ext_vector_type(8))) unsigned short usvec8;

__device__ __forceinline__ unsigned short f2bf(float f) {
    __hip_bfloat16 h = __float2bfloat16(f);
    return __builtin_bit_cast(unsigned short, h);
}
// XOR-swizzled LDS index: tiles are [rows][64] bf16; 16B unit index XORed with row&7.
__device__ __forceinline__ int lidx(int row, int k) {
    return row * 64 + (((k >> 3) ^ (row & 7)) << 3) + (k & 7);
}

// ---------------- dispatch: stable per-expert positions ----------------
__global__ void k_dispatch(const int* __restrict__ idx,
                           int* __restrict__ slot_token,
                           int* __restrict__ row_of,
                           int* __restrict__ cnt) {
    __shared__ int hist[256][E_];
    const int t = threadIdx.x;
#pragma unroll
    for (int e = 0; e < E_; e++) hist[t][e] = 0;
    __syncthreads();
    const int base = t * (N_ / 256);
    for (int j = 0; j < N_ / 256; j++) {
        int e = idx[base + j];
        hist[t][e]++;
    }
    __syncthreads();
    if (t < E_) {
        int run = 0;
        for (int i = 0; i < 256; i++) { int v = hist[i][t]; hist[i][t] = run; run += v; }
        cnt[t] = run < CAP_ ? run : CAP_;
    }
    for (int s = t; s < E_ * CAP_; s += 256) slot_token[s] = -1;
    __syncthreads();
    for (int j = 0; j < N_ / 256; j++) {
        int i = base + j;
        int e = idx[i];
        int p = hist[t][e]++;
        if (p < CAP_) { slot_token[e * CAP_ + p] = i; row_of[i] = e * CAP_ + p; }
        else          { row_of[i] = -1; }
    }
}

// ---------------- zero the (rare) dropped-token rows ----------------
__global__ void k_zero_dropped(const int* __restrict__ row_of, float* __restrict__ y) {
    const int i = blockIdx.x;
    if (row_of[i] >= 0) return;
    fvec4* yp = (fvec4*)(y + (size_t)i * D_);
    fvec4 z = {0.f, 0.f, 0.f, 0.f};
    for (int c = threadIdx.x; c < D_ / 4; c += 256) yp[c] = z;
}

// ---------------- gather x -> bf16 Abuf[E*CAP][D] ----------------
__global__ void k_gather(const float* __restrict__ x, const int* __restrict__ slot_token,
                         unsigned short* __restrict__ Abuf) {
    const int slot = blockIdx.x;
    const int t = slot_token[slot];
    usvec8* dst = (usvec8*)(Abuf + (size_t)slot * D_);
    if (t < 0) {
        usvec8 z = {0, 0, 0, 0, 0, 0, 0, 0};
        for (int c = threadIdx.x; c < D_ / 8; c += 256) dst[c] = z;
    } else {
        const fvec4* src = (const fvec4*)(x + (size_t)t * D_);
        for (int c = threadIdx.x; c < D_ / 8; c += 256) {
            fvec4 a = src[2 * c], b = src[2 * c + 1];
            usvec8 p = {f2bf(a[0]), f2bf(a[1]), f2bf(a[2]), f2bf(a[3]),
                        f2bf(b[0]), f2bf(b[1]), f2bf(b[2]), f2bf(b[3])};
            dst[c] = p;
        }
    }
}

// ================= GEMM1: H = silu(X*Wg) * (X*Wu) =================
// 64-row x 64-f tiles, grid 1760 (~6 blocks/CU) for latency hiding.
template <bool PRE>
__global__ __launch_bounds__(256, 4) void k_gemm1(
    const float* __restrict__ x, const unsigned short* __restrict__ Abuf,
    const float* __restrict__ Wg, const float* __restrict__ Wu,
    const int* __restrict__ slot_token, const int* __restrict__ cnt,
    unsigned short* __restrict__ H) {
    const int bid = blockIdx.x;           // 1760 = 8 xcd * 22 groups * 10 m
    const int xcd = bid & 7;
    const int j = bid >> 3;               // 0..219
    const int mb = j % 10;
    const int gl = j / 10;                // 0..21
    const int group = xcd * 22 + gl;      // 0..175
    const int e = group / 11, fidx = group % 11;
    const int m0 = mb * 64, f0 = fidx * 64;
    if (m0 >= cnt[e]) return;

    __shared__ __align__(16) unsigned short As[64 * 64];
    __shared__ __align__(16) unsigned short Bgs[64 * 64];
    __shared__ __align__(16) unsigned short Bus[64 * 64];
    __shared__ int tokS[64];

    const int tid = threadIdx.x;
    const int lane = tid & 63, wave = tid >> 6;
    const int wm = wave >> 1, wn = wave & 1;

    if (!PRE) {
        if (tid < 64) tokS[tid] = slot_token[e * CAP_ + m0 + tid];
        __syncthreads();
    }

    f32x4 accG[2][2], accU[2][2];
#pragma unroll
    for (int a = 0; a < 2; a++)
#pragma unroll
        for (int b = 0; b < 2; b++) {
            f32x4 z = {0.f, 0.f, 0.f, 0.f};
            accG[a][b] = z; accU[a][b] = z;
        }

    const int ar = tid >> 2, ak = (tid & 3) * 16;          // A: 4 lanes/row, 16 elems each
    const int fpos = (tid & 31) * 2, kq8 = (tid >> 5) * 8; // B: float2 per f-pair, 8 k's
    const int gf = f0 + fpos;
    const bool bvalid = gf < F_;                            // pair-safe (gf even, F even)
    const float2 fz2 = {0.f, 0.f};
    const float* WgE = Wg + (size_t)e * D_ * F_;
    const float* WuE = Wu + (size_t)e * D_ * F_;
    const unsigned short* Ae = Abuf + (size_t)(e * CAP_ + m0) * D_;

    for (int kc = 0; kc < D_; kc += 64) {
        // ---- stage A ----
        if (PRE) {
#pragma unroll
            for (int s = 0; s < 2; s++)
                *(usvec8*)&As[lidx(ar, ak + s * 8)] =
                    *(const usvec8*)&Ae[(size_t)ar * D_ + kc + ak + s * 8];
        } else {
            int t = tokS[ar];
            const float* src = x + (size_t)(t < 0 ? 0 : t) * D_ + kc + ak;
            fvec4 v0 = {0.f,0.f,0.f,0.f}, v1 = v0, v2 = v0, v3 = v0;
            if (t >= 0) { v0 = *(const fvec4*)src;        v1 = *(const fvec4*)(src + 4);
                          v2 = *(const fvec4*)(src + 8);  v3 = *(const fvec4*)(src + 12); }
            usvec8 p0 = {f2bf(v0[0]), f2bf(v0[1]), f2bf(v0[2]), f2bf(v0[3]),
                         f2bf(v1[0]), f2bf(v1[1]), f2bf(v1[2]), f2bf(v1[3])};
            usvec8 p1 = {f2bf(v2[0]), f2bf(v2[1]), f2bf(v2[2]), f2bf(v2[3]),
                         f2bf(v3[0]), f2bf(v3[1]), f2bf(v3[2]), f2bf(v3[3])};
            *(usvec8*)&As[lidx(ar, ak)] = p0;
            *(usvec8*)&As[lidx(ar, ak + 8)] = p1;
        }
        // ---- stage B (transposed to [f][k], k contiguous) ----
        {
            float2 g[8], u[8];
#pragma unroll
            for (int r = 0; r < 8; r++) {
                size_t off = (size_t)(kc + kq8 + r) * F_ + gf;
                g[r] = bvalid ? *(const float2*)(WgE + off) : fz2;
                u[r] = bvalid ? *(const float2*)(WuE + off) : fz2;
            }
            usvec8 pg0, pg1, pu0, pu1;
#pragma unroll
            for (int r = 0; r < 8; r++) {
                pg0[r] = (short)f2bf(g[r].x); pg1[r] = (short)f2bf(g[r].y);
                pu0[r] = (short)f2bf(u[r].x); pu1[r] = (short)f2bf(u[r].y);
            }
            *(usvec8*)&Bgs[lidx(fpos, kq8)]     = pg0;
            *(usvec8*)&Bgs[lidx(fpos + 1, kq8)] = pg1;
            *(usvec8*)&Bus[lidx(fpos, kq8)]     = pu0;
            *(usvec8*)&Bus[lidx(fpos + 1, kq8)] = pu1;
        }
        __syncthreads();
        // ---- compute ----
        __builtin_amdgcn_s_setprio(1);
#pragma unroll
        for (int kk = 0; kk < 64; kk += 32) {
            const int ko = kk + ((lane >> 4) << 3);
            bf16x8 av[2], bgv[2], buv[2];
#pragma unroll
            for (int mi = 0; mi < 2; mi++)
                av[mi] = *(const bf16x8*)&As[lidx(wm * 32 + mi * 16 + (lane & 15), ko)];
#pragma unroll
            for (int ni = 0; ni < 2; ni++) {
                int rr = wn * 32 + ni * 16 + (lane & 15);
                bgv[ni] = *(const bf16x8*)&Bgs[lidx(rr, ko)];
                buv[ni] = *(const bf16x8*)&Bus[lidx(rr, ko)];
            }
#pragma unroll
            for (int mi = 0; mi < 2; mi++)
#pragma unroll
                for (int ni = 0; ni < 2; ni++) {
                    accG[mi][ni] = __builtin_amdgcn_mfma_f32_16x16x32_bf16(av[mi], bgv[ni], accG[mi][ni], 0, 0, 0);
                    accU[mi][ni] = __builtin_amdgcn_mfma_f32_16x16x32_bf16(av[mi], buv[ni], accU[mi][ni], 0, 0, 0);
                }
        }
        __builtin_amdgcn_s_setprio(0);
        __syncthreads();
    }
    // ---- epilogue: fused SwiGLU, write bf16 H ----
#pragma unroll
    for (int mi = 0; mi < 2; mi++)
#pragma unroll
        for (int ni = 0; ni < 2; ni++) {
            int f = f0 + wn * 32 + ni * 16 + (lane & 15);
            if (f >= F_) continue;
            int rowb = m0 + wm * 32 + mi * 16 + ((lane >> 4) << 2);
#pragma unroll
            for (int q = 0; q < 4; q++) {
                float g = accG[mi][ni][q], u = accU[mi][ni][q];
                float h = g * u / (1.f + __expf(-g));
                H[(size_t)(e * CAP_ + rowb + q) * HS_ + f] = f2bf(h);
            }
        }
}

// ================= GEMM2: Y = H * Wd, scatter * score =================
__global__ __launch_bounds__(256, 4) void k_gemm2(
    const unsigned short* __restrict__ H, const float* __restrict__ Wd,
    const int* __restrict__ slot_token, const int* __restrict__ cnt,
    const float* __restrict__ scores, float* __restrict__ y) {
    const int bid = blockIdx.x;           // 5120 = 8 xcd * 128 groups * 5 m
    const int xcd = bid & 7;
    const int j = bid >> 3;
    const int mb = j % 5;
    const int gl = j / 5;
    const int group = xcd * 128 + gl;
    const int e = group >> 6, didx = group & 63;
    const int m0 = mb * 128, d0 = didx * 64;
    if (m0 >= cnt[e]) return;

    __shared__ __align__(16) unsigned short As[128 * 64];
    __shared__ __align__(16) unsigned short Bts[64 * 64];
    __shared__ int tokS[128];
    __shared__ float scS[128];

    const int tid = threadIdx.x;
    const int lane = tid & 63, wave = tid >> 6;
    const int wm = wave >> 1, wn = wave & 1;

    if (tid < 128) {
        int t = slot_token[e * CAP_ + m0 + tid];
        tokS[tid] = t;
        scS[tid] = (t >= 0) ? scores[t] : 0.f;
    }
    __syncthreads();

    f32x4 acc[4][2];
#pragma unroll
    for (int a = 0; a < 4; a++)
#pragma unroll
        for (int b = 0; b < 2; b++) {
            f32x4 z = {0.f, 0.f, 0.f, 0.f};
            acc[a][b] = z;
        }

    const int ar = tid >> 1, ak = (tid & 1) * 32;          // A: 2 lanes/row, 32 elems each
    const int dpos = (tid & 31) * 2, kq8 = (tid >> 5) * 8;
    const int gd = d0 + dpos;
    const float2 fz2 = {0.f, 0.f};
    const float* WdE = Wd + (size_t)e * F_ * D_;
    const unsigned short* He = H + (size_t)(e * CAP_ + m0) * HS_;

    for (int kc = 0; kc < 704; kc += 64) {   // 11 steps cover K = 688 (A pad reads ok, B=0)
        // ---- stage A from H (bf16, padded stride 704) ----
#pragma unroll
        for (int s = 0; s < 4; s++)
            *(usvec8*)&As[lidx(ar, ak + s * 8)] =
                *(const usvec8*)&He[(size_t)ar * HS_ + kc + ak + s * 8];
        // ---- stage B (Wd rows are K) ----
        {
            float2 b[8];
#pragma unroll
            for (int r = 0; r < 8; r++) {
                int kr = kc + kq8 + r;
                b[r] = (kr < F_) ? *(const float2*)(WdE + (size_t)kr * D_ + gd) : fz2;
            }
            usvec8 p0, p1;
#pragma unroll
            for (int r = 0; r < 8; r++) {
                p0[r] = (short)f2bf(b[r].x); p1[r] = (short)f2bf(b[r].y);
            }
            *(usvec8*)&Bts[lidx(dpos, kq8)]     = p0;
            *(usvec8*)&Bts[lidx(dpos + 1, kq8)] = p1;
        }
        __syncthreads();
        __builtin_amdgcn_s_setprio(1);
#pragma unroll
        for (int kk = 0; kk < 64; kk += 32) {
            const int ko = kk + ((lane >> 4) << 3);
            bf16x8 av[4], bv[2];
#pragma unroll
            for (int mi = 0; mi < 4; mi++)
                av[mi] = *(const bf16x8*)&As[lidx(wm * 64 + mi * 16 + (lane & 15), ko)];
#pragma unroll
            for (int ni = 0; ni < 2; ni++)
                bv[ni] = *(const bf16x8*)&Bts[lidx(wn * 32 + ni * 16 + (lane & 15), ko)];
#pragma unroll
            for (int mi = 0; mi < 4; mi++)
#pragma unroll
                for (int ni = 0; ni < 2; ni++)
                    acc[mi][ni] = __builtin_amdgcn_mfma_f32_16x16x32_bf16(av[mi], bv[ni], acc[mi][ni], 0, 0, 0);
        }
        __builtin_amdgcn_s_setprio(0);
        __syncthreads();
    }
    // ---- epilogue: scale by score, scatter to token rows ----
#pragma unroll
    for (int mi = 0; mi < 4; mi++)
#pragma unroll
        for (int ni = 0; ni < 2; ni++) {
            int d = d0 + wn * 32 + ni * 16 + (lane & 15);
            int rowb = wm * 64 + mi * 16 + ((lane >> 4) << 2);
#pragma unroll
            for (int q = 0; q < 4; q++) {
                int row = rowb + q;
                int t = tokS[row];
                if (t >= 0) y[(size_t)t * D_ + d] = acc[mi][ni][q] * scS[row];
            }
        }
}

extern "C" void kernel_launch(void* const* d_in, const int* in_sizes, int n_in,
                              void* d_out, int out_size, void* d_ws, size_t ws_size,
                              hipStream_t stream) {
    const float* x   = (const float*)d_in[0];
    const int*   idx = (const int*)d_in[1];
    const float* sc  = (const float*)d_in[2];
    const float* Wg  = (const float*)d_in[3];
    const float* Wu  = (const float*)d_in[4];
    const float* Wd  = (const float*)d_in[5];
    float* y = (float*)d_out;

    char* ws = (char*)d_ws;
    int* slot_token = (int*)ws;                              // E*CAP ints   = 40960 B
    int* row_of     = (int*)(ws + 40960);                    // N ints       = 32768 B
    int* cnt        = (int*)(ws + 40960 + 32768);            // E ints
    const size_t hoff = 131072;
    const size_t hbytes = (size_t)E_ * CAP_ * HS_ * 2;       // 14,417,920 B
    unsigned short* H = (unsigned short*)(ws + hoff);
    const size_t aoff = hoff + hbytes;
    const size_t abytes = (size_t)E_ * CAP_ * D_ * 2;        // 83,886,080 B
    unsigned short* Abuf = (unsigned short*)(ws + aoff);
    const bool pre = ws_size >= aoff + abytes;

    k_dispatch<<<1, 256, 0, stream>>>(idx, slot_token, row_of, cnt);
    k_zero_dropped<<<N_, 256, 0, stream>>>(row_of, y);
    if (pre) {
        k_gather<<<E_ * CAP_, 256, 0, stream>>>(x, slot_token, Abuf);
        k_gemm1<true><<<1760, 256, 0, stream>>>(x, Abuf, Wg, Wu, slot_token, cnt, H);
    } else {
        k_gemm1<false><<<1760, 256, 0, stream>>>(x, Abuf, Wg, Wu, slot_token, cnt, H);
    }
    k_gemm2<<<5120, 256, 0, stream>>>(H, Wd, slot_token, cnt, sc, y);
}

// Round 5
// 476.287 us; speedup vs baseline: 1.5483x; 1.1525x over previous
//
#include <hip/hip_runtime.h>
#include <hip/hip_bf16.h>

#define E_ 16
#define D_ 4096
#define F_ 688
#define N_ 8192
#define CAP_ 640     // int(1.25 * 8192 / 16)
#define NKT_ 64      // D/64 k-tiles
#define NFT_ 11      // ceil(F/64) f-tiles

typedef __attribute__((ext_vector_type(8))) short bf16x8;
typedef __attribute__((ext_vector_type(4))) float f32x4;
typedef __attribute__((ext_vector_type(4))) float fvec4;
typedef __attribute__((ext_vector_type(8))) unsigned short usvec8;

__device__ __forceinline__ unsigned short f2bf(float f) {
    __hip_bfloat16 h = __float2bfloat16(f);
    return __builtin_bit_cast(unsigned short, h);
}
// A-tile swizzle (128 rows x 64 k bf16): 16B unit XORed with row&7.
__device__ __forceinline__ int lidx(int row, int k) {
    return row * 64 + (((k >> 3) ^ (row & 7)) << 3) + (k & 7);
}
// B-tile swizzle (64 rows x 64 k): rows written in adjacent pairs -> XOR with (row>>1)&7
// so write (rows 2l,2l+1) and read (16 consecutive rows) both spread over all 8 quads.
__device__ __forceinline__ int bidx(int row, int k) {
    return row * 64 + (((k >> 3) ^ ((row >> 1) & 7)) << 3) + (k & 7);
}
// async global->LDS, 16B per lane; LDS dest is wave-uniform base (+ lane*16 in HW)
__device__ __forceinline__ void gload16(const unsigned short* g, unsigned short* l) {
    __builtin_amdgcn_global_load_lds(
        (const __attribute__((address_space(1))) unsigned int*)g,
        (__attribute__((address_space(3))) unsigned int*)l, 16, 0, 0);
}

// ---------------- dispatch: stable per-expert positions ----------------
__global__ void k_dispatch(const int* __restrict__ idx,
                           int* __restrict__ slot_token,
                           int* __restrict__ row_of,
                           int* __restrict__ cnt) {
    __shared__ int hist[256][E_];
    const int t = threadIdx.x;
#pragma unroll
    for (int e = 0; e < E_; e++) hist[t][e] = 0;
    __syncthreads();
    const int base = t * (N_ / 256);
    for (int j = 0; j < N_ / 256; j++) {
        int e = idx[base + j];
        hist[t][e]++;
    }
    __syncthreads();
    if (t < E_) {
        int run = 0;
        for (int i = 0; i < 256; i++) { int v = hist[i][t]; hist[i][t] = run; run += v; }
        cnt[t] = run < CAP_ ? run : CAP_;
    }
    for (int s = t; s < E_ * CAP_; s += 256) slot_token[s] = -1;
    __syncthreads();
    for (int j = 0; j < N_ / 256; j++) {
        int i = base + j;
        int e = idx[i];
        int p = hist[t][e]++;
        if (p < CAP_) { slot_token[e * CAP_ + p] = i; row_of[i] = e * CAP_ + p; }
        else          { row_of[i] = -1; }
    }
}

// ---------------- zero the (rare) dropped-token rows ----------------
__global__ void k_zero_dropped(const int* __restrict__ row_of, float* __restrict__ y) {
    const int i = blockIdx.x;
    if (row_of[i] >= 0) return;
    fvec4* yp = (fvec4*)(y + (size_t)i * D_);
    fvec4 z = {0.f, 0.f, 0.f, 0.f};
    for (int c = threadIdx.x; c < D_ / 4; c += 256) yp[c] = z;
}

// ---------------- gather x -> Aimg: pre-swizzled bf16 LDS-image tiles ----------------
// Aimg[strip][kt] is a 128x64 bf16 tile (16 KB) laid out exactly as the LDS image
// (lidx order), so gemm kernels can DMA it linearly with global_load_lds.
__global__ void k_gather(const float* __restrict__ x, const int* __restrict__ slot_token,
                         unsigned short* __restrict__ Aimg) {
    const int strip = blockIdx.y;       // 0..79  (= e*5 + mb)
    const int kg = blockIdx.x;          // 0..15  (4 k-tiles each)
    const int t = threadIdx.x;
    const int r = t >> 1, h = t & 1;
    const int tok = slot_token[strip * 128 + r];
#pragma unroll
    for (int kl4 = 0; kl4 < 4; kl4++) {
        const int kt = kg * 4 + kl4;
        const int k0 = kt * 64 + h * 32;
        unsigned short* dst = Aimg + ((size_t)strip * NKT_ + kt) * 8192;
        usvec8 p[4];
        if (tok < 0) {
            usvec8 z = {0, 0, 0, 0, 0, 0, 0, 0};
            p[0] = z; p[1] = z; p[2] = z; p[3] = z;
        } else {
            const float* src = x + (size_t)tok * D_ + k0;
#pragma unroll
            for (int uu = 0; uu < 4; uu++) {
                fvec4 a = *(const fvec4*)(src + uu * 8);
                fvec4 b = *(const fvec4*)(src + uu * 8 + 4);
                usvec8 q = {f2bf(a[0]), f2bf(a[1]), f2bf(a[2]), f2bf(a[3]),
                            f2bf(b[0]), f2bf(b[1]), f2bf(b[2]), f2bf(b[3])};
                p[uu] = q;
            }
        }
#pragma unroll
        for (int uu = 0; uu < 4; uu++)
            *(usvec8*)&dst[lidx(r, h * 32 + uu * 8)] = p[uu];
    }
}

// ================= GEMM1: H = silu(X*Wg) * (X*Wu) =================
// 128x64 tiles; A via async global_load_lds from Aimg (pre-swizzled);
// B (fp32 weights) reg-staged with T14 issue-early/write-late split.
__global__ __launch_bounds__(256, 2) void k_gemm1(
    const unsigned short* __restrict__ Aimg,
    const float* __restrict__ Wg, const float* __restrict__ Wu,
    const int* __restrict__ cnt, unsigned short* __restrict__ Himg) {
    const int bid = blockIdx.x;           // 880 = 8 xcd * 22 groups * 5 m
    const int xcd = bid & 7;
    const int j = bid >> 3;
    const int mb = j % 5;
    const int gl = j / 5;
    const int group = xcd * 22 + gl;      // 0..175
    const int e = group / NFT_, fidx = group % NFT_;
    const int m0 = mb * 128, f0 = fidx * 64;
    if (m0 >= cnt[e]) return;
    const int strip = e * 5 + mb;

    __shared__ __align__(16) unsigned short As[2][128 * 64];
    __shared__ __align__(16) unsigned short Bgs[2][64 * 64];
    __shared__ __align__(16) unsigned short Bus[2][64 * 64];

    const int tid = threadIdx.x;
    const int lane = tid & 63, wave = tid >> 6;
    const int wm = wave >> 1, wn = wave & 1;

    f32x4 accG[4][2], accU[4][2];
#pragma unroll
    for (int a = 0; a < 4; a++)
#pragma unroll
        for (int b = 0; b < 2; b++) {
            f32x4 z = {0.f, 0.f, 0.f, 0.f};
            accG[a][b] = z; accU[a][b] = z;
        }

    const int fpos = (tid & 31) * 2, kq8 = (tid >> 5) * 8;
    const int gf = f0 + fpos;
    const bool bvalid = gf < F_;          // pair-safe (gf even, F even)
    const float2 fz2 = {0.f, 0.f};
    const float* WgE = Wg + (size_t)e * D_ * F_;
    const float* WuE = Wu + (size_t)e * D_ * F_;
    const unsigned short* Astrip = Aimg + (size_t)strip * NKT_ * 8192;

    // ---- prologue: stage tile 0 ----
    {
#pragma unroll
        for (int i = 0; i < 4; i++) {
            int off = (wave * 4 + i) * 512;
            gload16(Astrip + off + lane * 8, &As[0][off]);
        }
        float2 g[8], u[8];
#pragma unroll
        for (int r = 0; r < 8; r++) {
            size_t off = (size_t)(kq8 + r) * F_ + gf;
            g[r] = bvalid ? *(const float2*)(WgE + off) : fz2;
            u[r] = bvalid ? *(const float2*)(WuE + off) : fz2;
        }
        usvec8 pg0, pg1, pu0, pu1;
#pragma unroll
        for (int r = 0; r < 8; r++) {
            pg0[r] = (short)f2bf(g[r].x); pg1[r] = (short)f2bf(g[r].y);
            pu0[r] = (short)f2bf(u[r].x); pu1[r] = (short)f2bf(u[r].y);
        }
        *(usvec8*)&Bgs[0][bidx(fpos, kq8)]     = pg0;
        *(usvec8*)&Bgs[0][bidx(fpos + 1, kq8)] = pg1;
        *(usvec8*)&Bus[0][bidx(fpos, kq8)]     = pu0;
        *(usvec8*)&Bus[0][bidx(fpos + 1, kq8)] = pu1;
    }
    __syncthreads();

    for (int kt = 0; kt < NKT_; ++kt) {
        const int cur = kt & 1, nxt = cur ^ 1;
        const bool hn = (kt + 1 < NKT_);
        float2 g[8], u[8];
        if (hn) {
            // issue next A DMA + B loads BEFORE the MFMA cluster (latency hides under it)
            const unsigned short* asrc = Astrip + (size_t)(kt + 1) * 8192;
#pragma unroll
            for (int i = 0; i < 4; i++) {
                int off = (wave * 4 + i) * 512;
                gload16(asrc + off + lane * 8, &As[nxt][off]);
            }
#pragma unroll
            for (int r = 0; r < 8; r++) {
                size_t off = ((size_t)(kt + 1) * 64 + kq8 + r) * F_ + gf;
                g[r] = bvalid ? *(const float2*)(WgE + off) : fz2;
                u[r] = bvalid ? *(const float2*)(WuE + off) : fz2;
            }
        }
        // ---- compute on cur ----
        __builtin_amdgcn_s_setprio(1);
#pragma unroll
        for (int kk = 0; kk < 64; kk += 32) {
            const int ko = kk + ((lane >> 4) << 3);
            bf16x8 av[4], bgv[2], buv[2];
#pragma unroll
            for (int mi = 0; mi < 4; mi++)
                av[mi] = *(const bf16x8*)&As[cur][lidx(wm * 64 + mi * 16 + (lane & 15), ko)];
#pragma unroll
            for (int ni = 0; ni < 2; ni++) {
                int rr = wn * 32 + ni * 16 + (lane & 15);
                bgv[ni] = *(const bf16x8*)&Bgs[cur][bidx(rr, ko)];
                buv[ni] = *(const bf16x8*)&Bus[cur][bidx(rr, ko)];
            }
#pragma unroll
            for (int mi = 0; mi < 4; mi++)
#pragma unroll
                for (int ni = 0; ni < 2; ni++) {
                    accG[mi][ni] = __builtin_amdgcn_mfma_f32_16x16x32_bf16(av[mi], bgv[ni], accG[mi][ni], 0, 0, 0);
                    accU[mi][ni] = __builtin_amdgcn_mfma_f32_16x16x32_bf16(av[mi], buv[ni], accU[mi][ni], 0, 0, 0);
                }
        }
        __builtin_amdgcn_s_setprio(0);
        if (hn) {
            usvec8 pg0, pg1, pu0, pu1;
#pragma unroll
            for (int r = 0; r < 8; r++) {
                pg0[r] = (short)f2bf(g[r].x); pg1[r] = (short)f2bf(g[r].y);
                pu0[r] = (short)f2bf(u[r].x); pu1[r] = (short)f2bf(u[r].y);
            }
            *(usvec8*)&Bgs[nxt][bidx(fpos, kq8)]     = pg0;
            *(usvec8*)&Bgs[nxt][bidx(fpos + 1, kq8)] = pg1;
            *(usvec8*)&Bus[nxt][bidx(fpos, kq8)]     = pu0;
            *(usvec8*)&Bus[nxt][bidx(fpos + 1, kq8)] = pu1;
        }
        __syncthreads();   // drains A DMA (vmcnt 0) + LDS writes for next tile
    }

    // ---- epilogue: fused SwiGLU -> Himg tile (LDS-image order, full 64 cols) ----
    unsigned short* Ht = Himg + ((size_t)strip * NFT_ + fidx) * 8192;
#pragma unroll
    for (int mi = 0; mi < 4; mi++)
#pragma unroll
        for (int ni = 0; ni < 2; ni++) {
            int fl = wn * 32 + ni * 16 + (lane & 15);
            int rl = wm * 64 + mi * 16 + ((lane >> 4) << 2);
#pragma unroll
            for (int q = 0; q < 4; q++) {
                float g = accG[mi][ni][q], u = accU[mi][ni][q];
                float h = g * u / (1.f + __expf(-g));
                Ht[lidx(rl + q, fl)] = f2bf(h);
            }
        }
}

// ================= GEMM2: Y = H * Wd, scatter * score =================
__global__ __launch_bounds__(256, 3) void k_gemm2(
    const unsigned short* __restrict__ Himg, const float* __restrict__ Wd,
    const int* __restrict__ slot_token, const int* __restrict__ cnt,
    const float* __restrict__ scores, float* __restrict__ y) {
    const int bid = blockIdx.x;           // 5120 = 8 xcd * 128 groups * 5 m
    const int xcd = bid & 7;
    const int j = bid >> 3;
    const int mb = j % 5;
    const int gl = j / 5;
    const int group = xcd * 128 + gl;
    const int e = group >> 6, didx = group & 63;
    const int m0 = mb * 128, d0 = didx * 64;
    if (m0 >= cnt[e]) return;
    const int strip = e * 5 + mb;

    __shared__ __align__(16) unsigned short As[2][128 * 64];
    __shared__ __align__(16) unsigned short Bts[2][64 * 64];
    __shared__ int tokS[128];
    __shared__ float scS[128];

    const int tid = threadIdx.x;
    const int lane = tid & 63, wave = tid >> 6;
    const int wm = wave >> 1, wn = wave & 1;

    if (tid < 128) {
        int t = slot_token[e * CAP_ + m0 + tid];
        tokS[tid] = t;
        scS[tid] = (t >= 0) ? scores[t] : 0.f;
    }

    f32x4 acc[4][2];
#pragma unroll
    for (int a = 0; a < 4; a++)
#pragma unroll
        for (int b = 0; b < 2; b++) {
            f32x4 z = {0.f, 0.f, 0.f, 0.f};
            acc[a][b] = z;
        }

    const int dpos = (tid & 31) * 2, kq8 = (tid >> 5) * 8;
    const int gd = d0 + dpos;
    const float2 fz2 = {0.f, 0.f};
    const float* WdE = Wd + (size_t)e * F_ * D_;
    const unsigned short* Hstrip = Himg + (size_t)strip * NFT_ * 8192;

    // ---- prologue: stage tile 0 ----
    {
#pragma unroll
        for (int i = 0; i < 4; i++) {
            int off = (wave * 4 + i) * 512;
            gload16(Hstrip + off + lane * 8, &As[0][off]);
        }
        float2 b[8];
#pragma unroll
        for (int r = 0; r < 8; r++) {
            int kr = kq8 + r;
            b[r] = (kr < F_) ? *(const float2*)(WdE + (size_t)kr * D_ + gd) : fz2;
        }
        usvec8 p0, p1;
#pragma unroll
        for (int r = 0; r < 8; r++) { p0[r] = (short)f2bf(b[r].x); p1[r] = (short)f2bf(b[r].y); }
        *(usvec8*)&Bts[0][bidx(dpos, kq8)]     = p0;
        *(usvec8*)&Bts[0][bidx(dpos + 1, kq8)] = p1;
    }
    __syncthreads();

    for (int fc = 0; fc < NFT_; ++fc) {
        const int cur = fc & 1, nxt = cur ^ 1;
        const bool hn = (fc + 1 < NFT_);
        float2 b[8];
        if (hn) {
            const unsigned short* asrc = Hstrip + (size_t)(fc + 1) * 8192;
#pragma unroll
            for (int i = 0; i < 4; i++) {
                int off = (wave * 4 + i) * 512;
                gload16(asrc + off + lane * 8, &As[nxt][off]);
            }
#pragma unroll
            for (int r = 0; r < 8; r++) {
                int kr = (fc + 1) * 64 + kq8 + r;
                b[r] = (kr < F_) ? *(const float2*)(WdE + (size_t)kr * D_ + gd) : fz2;
            }
        }
        __builtin_amdgcn_s_setprio(1);
#pragma unroll
        for (int kk = 0; kk < 64; kk += 32) {
            const int ko = kk + ((lane >> 4) << 3);
            bf16x8 av[4], bv[2];
#pragma unroll
            for (int mi = 0; mi < 4; mi++)
                av[mi] = *(const bf16x8*)&As[cur][lidx(wm * 64 + mi * 16 + (lane & 15), ko)];
#pragma unroll
            for (int ni = 0; ni < 2; ni++)
                bv[ni] = *(const bf16x8*)&Bts[cur][bidx(wn * 32 + ni * 16 + (lane & 15), ko)];
#pragma unroll
            for (int mi = 0; mi < 4; mi++)
#pragma unroll
                for (int ni = 0; ni < 2; ni++)
                    acc[mi][ni] = __builtin_amdgcn_mfma_f32_16x16x32_bf16(av[mi], bv[ni], acc[mi][ni], 0, 0, 0);
        }
        __builtin_amdgcn_s_setprio(0);
        if (hn) {
            usvec8 p0, p1;
#pragma unroll
            for (int r = 0; r < 8; r++) { p0[r] = (short)f2bf(b[r].x); p1[r] = (short)f2bf(b[r].y); }
            *(usvec8*)&Bts[nxt][bidx(dpos, kq8)]     = p0;
            *(usvec8*)&Bts[nxt][bidx(dpos + 1, kq8)] = p1;
        }
        __syncthreads();
    }

    // ---- epilogue: scale by score, scatter to token rows ----
#pragma unroll
    for (int mi = 0; mi < 4; mi++)
#pragma unroll
        for (int ni = 0; ni < 2; ni++) {
            int d = d0 + wn * 32 + ni * 16 + (lane & 15);
            int rowb = wm * 64 + mi * 16 + ((lane >> 4) << 2);
#pragma unroll
            for (int q = 0; q < 4; q++) {
                int row = rowb + q;
                int t = tokS[row];
                if (t >= 0) y[(size_t)t * D_ + d] = acc[mi][ni][q] * scS[row];
            }
        }
}

extern "C" void kernel_launch(void* const* d_in, const int* in_sizes, int n_in,
                              void* d_out, int out_size, void* d_ws, size_t ws_size,
                              hipStream_t stream) {
    const float* x   = (const float*)d_in[0];
    const int*   idx = (const int*)d_in[1];
    const float* sc  = (const float*)d_in[2];
    const float* Wg  = (const float*)d_in[3];
    const float* Wu  = (const float*)d_in[4];
    const float* Wd  = (const float*)d_in[5];
    float* y = (float*)d_out;

    char* ws = (char*)d_ws;
    int* slot_token = (int*)ws;                              // E*CAP ints   = 40960 B
    int* row_of     = (int*)(ws + 40960);                    // N ints       = 32768 B
    int* cnt        = (int*)(ws + 40960 + 32768);            // E ints
    const size_t hoff = 131072;
    const size_t hbytes = (size_t)80 * NFT_ * 8192 * 2;      // 14,417,920 B (H image)
    unsigned short* Himg = (unsigned short*)(ws + hoff);
    const size_t aoff = hoff + hbytes;
    unsigned short* Aimg = (unsigned short*)(ws + aoff);     // 80*64*8192*2 = 83,886,080 B

    k_dispatch<<<1, 256, 0, stream>>>(idx, slot_token, row_of, cnt);
    k_zero_dropped<<<N_, 256, 0, stream>>>(row_of, y);
    k_gather<<<dim3(16, 80), 256, 0, stream>>>(x, slot_token, Aimg);
    k_gemm1<<<880, 256, 0, stream>>>(Aimg, Wg, Wu, cnt, Himg);
    k_gemm2<<<5120, 256, 0, stream>>>(Himg, Wd, slot_token, cnt, sc, y);
}